// Round 11
// baseline (270.173 us; speedup 1.0000x reference)
//
#include <hip/hip_runtime.h>
#include <math.h>

#define HID 128
typedef unsigned int uint;
typedef __attribute__((ext_vector_type(8))) __bf16 bf16x8;
typedef __attribute__((ext_vector_type(4))) float f32x4;
typedef __attribute__((ext_vector_type(2))) float f32x2;

// ---------------- bf16 helpers (RNE) ----------------

__device__ __forceinline__ uint pack_bf2(float x, float y) {
    union { float f; uint u; } a, b;
    a.f = x; b.f = y;
    uint lo = (a.u + 0x7fffu + ((a.u >> 16) & 1u)) >> 16;
    uint hi = (b.u + 0x7fffu + ((b.u >> 16) & 1u)) & 0xffff0000u;
    return lo | hi;
}

__device__ __forceinline__ unsigned short bf16r(float x) {
    union { float f; uint u; } a; a.f = x;
    return (unsigned short)((a.u + 0x7fffu + ((a.u >> 16) & 1u)) >> 16);
}

__device__ __forceinline__ f32x2 bf2f(uint v) {
    union { uint u[2]; f32x2 f; } r;
    r.u[0] = v << 16;
    r.u[1] = v & 0xffff0000u;
    return r.f;
}

__device__ __forceinline__ f32x2 mk2(float s) { f32x2 r; r.x = s; r.y = s; return r; }
__device__ __forceinline__ f32x2 max2z(f32x2 a) {
    f32x2 r; r.x = fmaxf(a.x, 0.f); r.y = fmaxf(a.y, 0.f); return r;
}
__device__ __forceinline__ f32x2 shfl_xor2(f32x2 v, int m) {
    f32x2 r; r.x = __shfl_xor(v.x, m, 64); r.y = __shfl_xor(v.y, m, 64); return r;
}

// ---------------- setup kernels ----------------

// composite weights only (cnt zeroed via hipMemsetAsync):
//   Wc = W2 @ [Wm1_top | Wm1_mid]  (128 x 256), bf16 MFMA frag order
//   brow = b2 @ [Wm1_top | Wm1_mid] + [bm1 | 0]  (256)
__global__ void prep_kernel(const float* __restrict__ W2, const float* __restrict__ Wm1,
                            const float* __restrict__ b2, const float* __restrict__ bm1,
                            uint* __restrict__ fWc, float* __restrict__ brow) {
    int t0 = blockIdx.x * blockDim.x + threadIdx.x;
    if (t0 < 16384) {       // 16 ct * 4 kk * 64 lanes * 4 pairs
        int i = t0;
        int p = i & 3, lane = (i >> 2) & 63, kk = (i >> 8) & 3, ct = i >> 10;
        int k = kk * 32 + (lane >> 4) * 8 + p * 2;
        int n2 = ct * 16 + (lane & 15);
        const float* wmc = (n2 < 128) ? (Wm1 + n2) : (Wm1 + 128 * HID + (n2 - 128));
        const float* w2r0 = W2 + (size_t)k * HID;
        const float* w2r1 = w2r0 + HID;
        float d0 = 0.f, d1 = 0.f;
        for (int j = 0; j < HID; ++j) {
            float wm = wmc[(size_t)j * HID];
            d0 += w2r0[j] * wm;
            d1 += w2r1[j] * wm;
        }
        fWc[i] = pack_bf2(d0, d1);
    } else if (t0 < 16384 + 256) {
        int i = t0 - 16384;
        const float* wmc = (i < 128) ? (Wm1 + i) : (Wm1 + 128 * HID + (i - 128));
        float d = 0.f;
        for (int j = 0; j < HID; ++j) d += b2[j] * wmc[(size_t)j * HID];
        brow[i] = d + ((i < 128) ? bm1[i] : 0.f);
    }
}

// histogram + within-bucket rank (atomic return value)
__global__ void hist_rank(const int* __restrict__ dst, int* __restrict__ cnt,
                          int* __restrict__ rank, int E) {
    int e = blockIdx.x * blockDim.x + threadIdx.x;
    if (e < E) rank[e] = atomicAdd(&cnt[dst[e]], 1);
}

__global__ void scan1(const int* __restrict__ cnt, int* __restrict__ excl,
                      int* __restrict__ bsum, int N) {
    __shared__ int sh[256];
    int tid = threadIdx.x;
    int gid = blockIdx.x * 256 + tid;
    int v = (gid < N) ? cnt[gid] : 0;
    sh[tid] = v;
    __syncthreads();
    for (int o = 1; o < 256; o <<= 1) {
        int t = (tid >= o) ? sh[tid - o] : 0;
        __syncthreads();
        sh[tid] += t;
        __syncthreads();
    }
    if (gid < N) excl[gid] = sh[tid] - v;
    if (tid == 255) bsum[blockIdx.x] = sh[255];
}

// every block redundantly scans bsum in LDS, finalizes rowptr/dis,
// and writes xps[n] = bf16( dis[n] * x[n] ) packed into uint4 (5 dims + pad)
__global__ void scan3x(const int* __restrict__ cnt, int* __restrict__ rowptr,
                       const int* __restrict__ bsum,
                       float* __restrict__ dis, const float* __restrict__ x,
                       uint4* __restrict__ xps, int N, int E, int NB) {
    __shared__ int sh[256];
    __shared__ int ex[256];
    int tid = threadIdx.x;
    int v = (tid < NB) ? bsum[tid] : 0;
    sh[tid] = v;
    __syncthreads();
    for (int o = 1; o < 256; o <<= 1) {
        int t = (tid >= o) ? sh[tid - o] : 0;
        __syncthreads();
        sh[tid] += t;
        __syncthreads();
    }
    ex[tid] = sh[tid] - v;
    __syncthreads();
    int gid = blockIdx.x * 256 + tid;
    if (gid < N) {
        rowptr[gid] = rowptr[gid] + ex[blockIdx.x];
        float dn = rsqrtf((float)cnt[gid] + 1.0f);   // deg incl. self-loop
        dis[gid] = dn;
        const float* xr = x + (size_t)gid * 5;
        uint4 pk;
        pk.x = pack_bf2(dn * xr[0], dn * xr[1]);
        pk.y = pack_bf2(dn * xr[2], dn * xr[3]);
        pk.z = pack_bf2(dn * xr[4], 0.f);
        pk.w = 0u;
        xps[gid] = pk;
    }
    if (gid == N) rowptr[N] = E;
}

// atomic-free scatter: pos = rowptr[dst] + rank; csr2[pos] = (src|dst<<16, eid)
__global__ void scatter2(const int* __restrict__ src, const int* __restrict__ dst,
                         const int* __restrict__ rowptr, const int* __restrict__ rank,
                         uint2* __restrict__ csr2, int E) {
    int e = blockIdx.x * blockDim.x + threadIdx.x;
    if (e < E) {
        int d = dst[e];
        int pos = rowptr[d] + rank[e];
        csr2[pos] = make_uint2((uint)src[e] | ((uint)d << 16), (uint)e);
    }
}

// ---------------- fused layer-1: hs1 = dis * relu( (S·x) @ W1 + b1 ) ----------------
// one thread per node: 5-dim aggregate (bf16 xps, 16 B rows), 128-col LDS-W1 expansion.
__launch_bounds__(256)
__global__ void layer1_kernel(const uint4* __restrict__ xps, const uint2* __restrict__ csr2,
                              const int* __restrict__ rowptr, const float* __restrict__ dis,
                              const float* __restrict__ W1, const float* __restrict__ b1,
                              uint* __restrict__ hs1, int N) {
    __shared__ float sW[5 * HID];
    __shared__ float sb[HID];
    int tid = threadIdx.x;
    for (int i = tid; i < 5 * HID; i += 256) sW[i] = W1[i];
    for (int i = tid; i < HID; i += 256) sb[i] = b1[i];
    __syncthreads();

    int n = blockIdx.x * 256 + tid;
    if (n >= N) return;
    int beg = rowptr[n], end = rowptr[n + 1];
    float a0 = 0.f, a1 = 0.f, a2 = 0.f, a3 = 0.f, a4 = 0.f;
    for (int i = beg; i < end; ++i) {
        int s = (int)(csr2[i].x & 0xffffu);
        uint4 v = xps[s];
        f32x2 v01 = bf2f(v.x), v23 = bf2f(v.y), v4 = bf2f(v.z);
        a0 += v01.x; a1 += v01.y; a2 += v23.x; a3 += v23.y; a4 += v4.x;
    }
    {
        uint4 v = xps[n];
        f32x2 v01 = bf2f(v.x), v23 = bf2f(v.y), v4 = bf2f(v.z);
        a0 += v01.x; a1 += v01.y; a2 += v23.x; a3 += v23.y; a4 += v4.x;
    }
    float dn = dis[n];
    a0 *= dn; a1 *= dn; a2 *= dn; a3 *= dn; a4 *= dn;   // sx row

    uint* op = hs1 + (size_t)n * 64;
    #pragma unroll 4
    for (int p = 0; p < 64; ++p) {
        int j = p * 2;
        float t0 = sb[j]     + a0 * sW[j]     + a1 * sW[HID + j]     + a2 * sW[2*HID + j]
                             + a3 * sW[3*HID + j] + a4 * sW[4*HID + j];
        float t1 = sb[j + 1] + a0 * sW[j + 1] + a1 * sW[HID + j + 1] + a2 * sW[2*HID + j + 1]
                             + a3 * sW[3*HID + j + 1] + a4 * sW[4*HID + j + 1];
        op[p] = pack_bf2(fmaxf(t0, 0.f) * dn, fmaxf(t1, 0.f) * dn);
    }
}

// ---------------- fused aggregate + GEMM ----------------
// block = 4 waves = 16 nodes.  Phase 1: wave aggregates 4 nodes (16-lane group per
// edge, 4-deep) into LDS tile g[16][128] bf16.  Phase 2: wave MFMAs the tile against
// 4 of 16 column-tiles of Wc, writes HsHd rows (+brow bias).
__launch_bounds__(256)
__global__ void agg_gemm(const uint4* __restrict__ hs1, const uint2* __restrict__ csr2,
                         const int* __restrict__ rowptr, const float* __restrict__ dis,
                         const uint4* __restrict__ Bf, const float* __restrict__ brow,
                         unsigned short* __restrict__ out, int N) {
    __shared__ uint gt[16][64];
    int wave = threadIdx.x >> 6, lane = threadIdx.x & 63;
    int gl = lane & 15, grp = lane >> 4;
    int nb = blockIdx.x * 16;

    for (int q = 0; q < 4; ++q) {
        int r = wave * 4 + q;
        int n = nb + r;
        if (n < N) {
            int beg = rowptr[n], end = rowptr[n + 1];
            f32x2 acc[4];
            #pragma unroll
            for (int p = 0; p < 4; ++p) acc[p] = mk2(0.f);
            for (int base = beg + grp; base < end; base += 16) {
                int i1 = base + 4, i2 = base + 8, i3 = base + 12;
                int s0 = (int)(csr2[base].x & 0xffffu);
                int s1 = (int)(csr2[(i1 < end) ? i1 : beg].x & 0xffffu);
                int s2 = (int)(csr2[(i2 < end) ? i2 : beg].x & 0xffffu);
                int s3 = (int)(csr2[(i3 < end) ? i3 : beg].x & 0xffffu);
                uint4 v0 = hs1[(size_t)s0 * 16 + gl];
                uint4 v1 = hs1[(size_t)s1 * 16 + gl];
                uint4 v2 = hs1[(size_t)s2 * 16 + gl];
                uint4 v3 = hs1[(size_t)s3 * 16 + gl];
                f32x2 w1 = mk2((i1 < end) ? 1.f : 0.f);
                f32x2 w2 = mk2((i2 < end) ? 1.f : 0.f);
                f32x2 w3 = mk2((i3 < end) ? 1.f : 0.f);
                acc[0] += bf2f(v0.x);  acc[1] += bf2f(v0.y);
                acc[2] += bf2f(v0.z);  acc[3] += bf2f(v0.w);
                acc[0] += bf2f(v1.x) * w1;  acc[1] += bf2f(v1.y) * w1;
                acc[2] += bf2f(v1.z) * w1;  acc[3] += bf2f(v1.w) * w1;
                acc[0] += bf2f(v2.x) * w2;  acc[1] += bf2f(v2.y) * w2;
                acc[2] += bf2f(v2.z) * w2;  acc[3] += bf2f(v2.w) * w2;
                acc[0] += bf2f(v3.x) * w3;  acc[1] += bf2f(v3.y) * w3;
                acc[2] += bf2f(v3.z) * w3;  acc[3] += bf2f(v3.w) * w3;
            }
            #pragma unroll
            for (int p = 0; p < 4; ++p) {
                acc[p] += shfl_xor2(acc[p], 16);
                acc[p] += shfl_xor2(acc[p], 32);
            }
            if (grp == 0) {
                uint4 sv = hs1[(size_t)n * 16 + gl];
                f32x2 dn = mk2(dis[n]);
                f32x2 o0 = (acc[0] + bf2f(sv.x)) * dn;
                f32x2 o1 = (acc[1] + bf2f(sv.y)) * dn;
                f32x2 o2 = (acc[2] + bf2f(sv.z)) * dn;
                f32x2 o3 = (acc[3] + bf2f(sv.w)) * dn;
                gt[r][gl * 4]     = pack_bf2(o0.x, o0.y);
                gt[r][gl * 4 + 1] = pack_bf2(o1.x, o1.y);
                gt[r][gl * 4 + 2] = pack_bf2(o2.x, o2.y);
                gt[r][gl * 4 + 3] = pack_bf2(o3.x, o3.y);
            }
        } else if (grp == 0) {
            gt[r][gl * 4] = 0; gt[r][gl * 4 + 1] = 0;
            gt[r][gl * 4 + 2] = 0; gt[r][gl * 4 + 3] = 0;
        }
    }
    __syncthreads();

    int quad = lane >> 4;
    bf16x8 afr[4];
    #pragma unroll
    for (int kk = 0; kk < 4; ++kk)
        afr[kk] = *(const bf16x8*)&gt[gl][kk * 16 + quad * 4];

    for (int cc = 0; cc < 4; ++cc) {
        int c = wave * 4 + cc;
        f32x4 acc = {0.f, 0.f, 0.f, 0.f};
        #pragma unroll
        for (int kk = 0; kk < 4; ++kk) {
            bf16x8 bfr = *(const bf16x8*)&Bf[(size_t)(c * 4 + kk) * 64 + lane];
            acc = __builtin_amdgcn_mfma_f32_16x16x32_bf16(afr[kk], bfr, acc, 0, 0, 0);
        }
        float bv = brow[c * 16 + gl];
        #pragma unroll
        for (int reg = 0; reg < 4; ++reg) {
            int row = nb + quad * 4 + reg;
            if (row < N)
                out[(size_t)row * 256 + c * 16 + gl] = bf16r(acc[reg] + bv);
        }
    }
}

// edge-parallel edge MLP, per-wave CONTIGUOUS chunks + XCD-aware block swizzle:
// each XCD covers a contiguous dst range -> Hd/ea working set fits its 4 MB L2.
__launch_bounds__(256)
__global__ void edge_mlp_kernel(const uint4* __restrict__ HsHd, const float4* __restrict__ ea,
                                const uint2* __restrict__ csr2,
                                const float* __restrict__ Wb, const float* __restrict__ Wm2,
                                const float* __restrict__ bm2,
                                float* __restrict__ out, int E) {
    int lane = threadIdx.x & 63;
    int wave = threadIdx.x >> 6;
    int gl = lane & 15, grp = lane >> 4;

    f32x2 wb[4][4], w2[4];
    #pragma unroll
    for (int k = 0; k < 4; ++k) {
        const f32x2* wp = (const f32x2*)(Wb + k * HID + gl * 8);
        #pragma unroll
        for (int p = 0; p < 4; ++p) wb[k][p] = wp[p];
    }
    {
        const f32x2* wp = (const f32x2*)(Wm2 + gl * 8);
        #pragma unroll
        for (int p = 0; p < 4; ++p) w2[p] = wp[p];
    }
    float b2v = bm2[0];

    // XCD swizzle: blocks dispatch round-robin over 8 XCDs; give XCD k the
    // contiguous logical-block range [k*nb/8, (k+1)*nb/8).
    int nb = gridDim.x;                     // multiple of 8
    int lb = (blockIdx.x & 7) * (nb >> 3) + (blockIdx.x >> 3);
    int lw = lb * (blockDim.x >> 6) + wave;
    int nw = (nb * blockDim.x) >> 6;
    long chunk = (((long)E + (long)nw * 16 - 1) / ((long)nw * 16)) * 16;
    long s64 = (long)lw * chunk;
    int start = (s64 < E) ? (int)s64 : E;
    long e64 = s64 + chunk;
    int stop = (e64 < E) ? (int)e64 : E;

    for (int base = start; base < stop; base += 16) {
        int i0 = base + grp * 4;
        uint2 ce[4];
        uint4 hv[4], dv[4];
        float4 eav[4];
        #pragma unroll
        for (int t = 0; t < 4; ++t) {
            int i = i0 + t;
            int j = (i < E) ? i : (E - 1);
            ce[t] = csr2[j];
            hv[t] = HsHd[(size_t)(ce[t].x & 0xffffu) * 32 + gl];
            dv[t] = HsHd[(size_t)(ce[t].x >> 16) * 32 + 16 + gl];
            eav[t] = ea[ce[t].y];
        }
        float pr[4];
        #pragma unroll
        for (int t = 0; t < 4; ++t) {
            uint hu[4] = {hv[t].x, hv[t].y, hv[t].z, hv[t].w};
            uint du[4] = {dv[t].x, dv[t].y, dv[t].z, dv[t].w};
            f32x2 e0 = mk2(eav[t].x), e1 = mk2(eav[t].y);
            f32x2 e2 = mk2(eav[t].z), e3 = mk2(eav[t].w);
            f32x2 p2 = mk2(0.f);
            #pragma unroll
            for (int p = 0; p < 4; ++p) {
                f32x2 tt = bf2f(hu[p]) + bf2f(du[p]);
                tt += e0 * wb[0][p];
                tt += e1 * wb[1][p];
                tt += e2 * wb[2][p];
                tt += e3 * wb[3][p];
                tt = max2z(tt);
                p2 += tt * w2[p];
            }
            pr[t] = p2.x + p2.y;
        }
        #pragma unroll
        for (int o = 1; o <= 8; o <<= 1) {
            #pragma unroll
            for (int t = 0; t < 4; ++t) pr[t] += __shfl_xor(pr[t], o, 64);
        }
        if (gl == 0) {
            #pragma unroll
            for (int t = 0; t < 4; ++t) {
                int i = i0 + t;
                if (i < E)
                    out[ce[t].y] = 1.f / (1.f + exp2f(-1.44269504f * (pr[t] + b2v)));
            }
        }
    }
}

// ---------------- launch ----------------

extern "C" void kernel_launch(void* const* d_in, const int* in_sizes, int n_in,
                              void* d_out, int out_size, void* d_ws, size_t ws_size,
                              hipStream_t stream) {
    const float* x    = (const float*)d_in[0];
    const float* ea   = (const float*)d_in[1];
    const float* W1   = (const float*)d_in[2];
    const float* b1   = (const float*)d_in[3];
    const float* W2   = (const float*)d_in[4];
    const float* b2   = (const float*)d_in[5];
    const float* Wm1  = (const float*)d_in[6];
    const float* bm1  = (const float*)d_in[7];
    const float* Wm2  = (const float*)d_in[8];
    const float* bm2  = (const float*)d_in[9];
    const int*   ei   = (const int*)d_in[10];

    const int N = in_sizes[0] / 5;
    const int E = in_sizes[1] / 4;
    const int* src = ei;
    const int* dst = ei + E;
    float* out = (float*)d_out;

    char* ws = (char*)d_ws;
    size_t off = 0;
    auto alloc = [&](size_t bytes) -> void* {
        void* p = ws + off;
        off = (off + bytes + 255) & ~(size_t)255;
        return p;
    };
    int*    cnt    = (int*)alloc((size_t)N * 4);
    int*    rowptr = (int*)alloc((size_t)(N + 1) * 4);
    int*    bsum   = (int*)alloc(256 * 4);
    float*  dis    = (float*)alloc((size_t)N * 4);
    int*    rank   = (int*)alloc((size_t)(E + 8) * 4);
    uint2*  csr2   = (uint2*)alloc((size_t)(E + 8) * 8);
    uint4*  xps    = (uint4*)alloc((size_t)N * 16);      // bf16 dis*x, 16 B rows
    uint*   hs1    = (uint*)alloc((size_t)N * 64 * 4);   // bf16 layer-1 features
    uint*   HsHd   = (uint*)alloc((size_t)N * 128 * 4);  // bf16 [N][256]
    uint*   fWc    = (uint*)alloc(16384 * 4);
    float*  brow   = (float*)alloc(256 * 4);
    (void)ws_size; (void)n_in; (void)out_size;

    const int NB = (N + 255) / 256;
    const int EB = (E + 255) / 256;

    // setup
    hipMemsetAsync(cnt, 0, (size_t)N * 4, stream);
    prep_kernel<<<65, 256, 0, stream>>>(W2, Wm1, b2, bm1, fWc, brow);
    hist_rank<<<EB, 256, 0, stream>>>(dst, cnt, rank, E);
    scan1<<<NB, 256, 0, stream>>>(cnt, rowptr, bsum, N);
    scan3x<<<NB, 256, 0, stream>>>(cnt, rowptr, bsum, dis, x, xps, N, E, NB);
    scatter2<<<EB, 256, 0, stream>>>(src, dst, rowptr, rank, csr2, E);

    // layer 1 fused: hs1 = dis * relu((S·x)@W1 + b1)
    layer1_kernel<<<NB, 256, 0, stream>>>(xps, csr2, rowptr, dis, W1, b1, hs1, N);

    // fused: g = S·h1 (LDS tile) ; HsHd = g @ Wc + brow
    agg_gemm<<<(N + 15) / 16, 256, 0, stream>>>((const uint4*)hs1, csr2, rowptr, dis,
                                                (const uint4*)fWc, brow,
                                                (unsigned short*)HsHd, N);

    // per-edge MLP + sigmoid, dst-sorted order, XCD-local chunks
    edge_mlp_kernel<<<2048, 256, 0, stream>>>((const uint4*)HsHd, (const float4*)ea, csr2,
                                              Wm1 + 256 * HID, Wm2, bm2, out, E);
}

// Round 12
// 265.367 us; speedup vs baseline: 1.0181x; 1.0181x over previous
//
#include <hip/hip_runtime.h>
#include <math.h>

#define HID 128
typedef unsigned int uint;
typedef __attribute__((ext_vector_type(8))) __bf16 bf16x8;
typedef __attribute__((ext_vector_type(4))) float f32x4;
typedef __attribute__((ext_vector_type(2))) float f32x2;

// ---------------- bf16 helpers (RNE) ----------------

__device__ __forceinline__ uint pack_bf2(float x, float y) {
    union { float f; uint u; } a, b;
    a.f = x; b.f = y;
    uint lo = (a.u + 0x7fffu + ((a.u >> 16) & 1u)) >> 16;
    uint hi = (b.u + 0x7fffu + ((b.u >> 16) & 1u)) & 0xffff0000u;
    return lo | hi;
}

__device__ __forceinline__ unsigned short bf16r(float x) {
    union { float f; uint u; } a; a.f = x;
    return (unsigned short)((a.u + 0x7fffu + ((a.u >> 16) & 1u)) >> 16);
}

__device__ __forceinline__ f32x2 bf2f(uint v) {
    union { uint u[2]; f32x2 f; } r;
    r.u[0] = v << 16;
    r.u[1] = v & 0xffff0000u;
    return r.f;
}

__device__ __forceinline__ f32x2 mk2(float s) { f32x2 r; r.x = s; r.y = s; return r; }
__device__ __forceinline__ f32x2 max2z(f32x2 a) {
    f32x2 r; r.x = fmaxf(a.x, 0.f); r.y = fmaxf(a.y, 0.f); return r;
}
__device__ __forceinline__ f32x2 shfl_xor2(f32x2 v, int m) {
    f32x2 r; r.x = __shfl_xor(v.x, m, 64); r.y = __shfl_xor(v.y, m, 64); return r;
}

// ---------------- setup kernels ----------------

// composite weights (cnt zeroed via hipMemsetAsync):
//   Wc = W2 @ [Wm1_top | Wm1_mid]  (128 x 256), bf16 MFMA frag order
//   brow = b2 @ [Wm1_top | Wm1_mid] + [bm1 | 0]  (256)
__global__ void prep_kernel(const float* __restrict__ W2, const float* __restrict__ Wm1,
                            const float* __restrict__ b2, const float* __restrict__ bm1,
                            uint* __restrict__ fWc, float* __restrict__ brow) {
    int t0 = blockIdx.x * blockDim.x + threadIdx.x;
    if (t0 < 16384) {       // 16 ct * 4 kk * 64 lanes * 4 pairs
        int i = t0;
        int p = i & 3, lane = (i >> 2) & 63, kk = (i >> 8) & 3, ct = i >> 10;
        int k = kk * 32 + (lane >> 4) * 8 + p * 2;
        int n2 = ct * 16 + (lane & 15);
        const float* wmc = (n2 < 128) ? (Wm1 + n2) : (Wm1 + 128 * HID + (n2 - 128));
        const float* w2r0 = W2 + (size_t)k * HID;
        const float* w2r1 = w2r0 + HID;
        float d0 = 0.f, d1 = 0.f;
        for (int j = 0; j < HID; ++j) {
            float wm = wmc[(size_t)j * HID];
            d0 += w2r0[j] * wm;
            d1 += w2r1[j] * wm;
        }
        fWc[i] = pack_bf2(d0, d1);
    } else if (t0 < 16384 + 256) {
        int i = t0 - 16384;
        const float* wmc = (i < 128) ? (Wm1 + i) : (Wm1 + 128 * HID + (i - 128));
        float d = 0.f;
        for (int j = 0; j < HID; ++j) d += b2[j] * wmc[(size_t)j * HID];
        brow[i] = d + ((i < 128) ? bm1[i] : 0.f);
    }
}

// histogram + within-bucket rank (atomic return value)
__global__ void hist_rank(const int* __restrict__ dst, int* __restrict__ cnt,
                          int* __restrict__ rank, int E) {
    int e = blockIdx.x * blockDim.x + threadIdx.x;
    if (e < E) rank[e] = atomicAdd(&cnt[dst[e]], 1);
}

__global__ void scan1(const int* __restrict__ cnt, int* __restrict__ excl,
                      int* __restrict__ bsum, int N) {
    __shared__ int sh[256];
    int tid = threadIdx.x;
    int gid = blockIdx.x * 256 + tid;
    int v = (gid < N) ? cnt[gid] : 0;
    sh[tid] = v;
    __syncthreads();
    for (int o = 1; o < 256; o <<= 1) {
        int t = (tid >= o) ? sh[tid - o] : 0;
        __syncthreads();
        sh[tid] += t;
        __syncthreads();
    }
    if (gid < N) excl[gid] = sh[tid] - v;
    if (tid == 255) bsum[blockIdx.x] = sh[255];
}

// every block redundantly scans bsum in LDS, finalizes rowptr/dis,
// and writes xps[n] = bf16( dis[n] * x[n] ) packed into uint4 (5 dims + pad)
__global__ void scan3x(const int* __restrict__ cnt, int* __restrict__ rowptr,
                       const int* __restrict__ bsum,
                       float* __restrict__ dis, const float* __restrict__ x,
                       uint4* __restrict__ xps, int N, int E, int NB) {
    __shared__ int sh[256];
    __shared__ int ex[256];
    int tid = threadIdx.x;
    int v = (tid < NB) ? bsum[tid] : 0;
    sh[tid] = v;
    __syncthreads();
    for (int o = 1; o < 256; o <<= 1) {
        int t = (tid >= o) ? sh[tid - o] : 0;
        __syncthreads();
        sh[tid] += t;
        __syncthreads();
    }
    ex[tid] = sh[tid] - v;
    __syncthreads();
    int gid = blockIdx.x * 256 + tid;
    if (gid < N) {
        rowptr[gid] = rowptr[gid] + ex[blockIdx.x];
        float dn = rsqrtf((float)cnt[gid] + 1.0f);   // deg incl. self-loop
        dis[gid] = dn;
        const float* xr = x + (size_t)gid * 5;
        uint4 pk;
        pk.x = pack_bf2(dn * xr[0], dn * xr[1]);
        pk.y = pack_bf2(dn * xr[2], dn * xr[3]);
        pk.z = pack_bf2(dn * xr[4], 0.f);
        pk.w = 0u;
        xps[gid] = pk;
    }
    if (gid == N) rowptr[N] = E;
}

// atomic-free scatter: pos = rowptr[dst] + rank; csr2[pos] = (src|dst<<16, eid)
__global__ void scatter2(const int* __restrict__ src, const int* __restrict__ dst,
                         const int* __restrict__ rowptr, const int* __restrict__ rank,
                         uint2* __restrict__ csr2, int E) {
    int e = blockIdx.x * blockDim.x + threadIdx.x;
    if (e < E) {
        int d = dst[e];
        int pos = rowptr[d] + rank[e];
        csr2[pos] = make_uint2((uint)src[e] | ((uint)d << 16), (uint)e);
    }
}

// ---------------- fused layer-1: hs1 = dis * relu( (S·x) @ W1 + b1 ) ----------------
// one thread per node: 5-dim aggregate (bf16 xps, 16 B rows), 128-col LDS-W1 expansion.
__launch_bounds__(256)
__global__ void layer1_kernel(const uint4* __restrict__ xps, const uint2* __restrict__ csr2,
                              const int* __restrict__ rowptr, const float* __restrict__ dis,
                              const float* __restrict__ W1, const float* __restrict__ b1,
                              uint* __restrict__ hs1, int N) {
    __shared__ float sW[5 * HID];
    __shared__ float sb[HID];
    int tid = threadIdx.x;
    for (int i = tid; i < 5 * HID; i += 256) sW[i] = W1[i];
    for (int i = tid; i < HID; i += 256) sb[i] = b1[i];
    __syncthreads();

    int n = blockIdx.x * 256 + tid;
    if (n >= N) return;
    int beg = rowptr[n], end = rowptr[n + 1];
    float a0 = 0.f, a1 = 0.f, a2 = 0.f, a3 = 0.f, a4 = 0.f;
    for (int i = beg; i < end; ++i) {
        int s = (int)(csr2[i].x & 0xffffu);
        uint4 v = xps[s];
        f32x2 v01 = bf2f(v.x), v23 = bf2f(v.y), v4 = bf2f(v.z);
        a0 += v01.x; a1 += v01.y; a2 += v23.x; a3 += v23.y; a4 += v4.x;
    }
    {
        uint4 v = xps[n];
        f32x2 v01 = bf2f(v.x), v23 = bf2f(v.y), v4 = bf2f(v.z);
        a0 += v01.x; a1 += v01.y; a2 += v23.x; a3 += v23.y; a4 += v4.x;
    }
    float dn = dis[n];
    a0 *= dn; a1 *= dn; a2 *= dn; a3 *= dn; a4 *= dn;   // sx row

    uint* op = hs1 + (size_t)n * 64;
    #pragma unroll 4
    for (int p = 0; p < 64; ++p) {
        int j = p * 2;
        float t0 = sb[j]     + a0 * sW[j]     + a1 * sW[HID + j]     + a2 * sW[2*HID + j]
                             + a3 * sW[3*HID + j] + a4 * sW[4*HID + j];
        float t1 = sb[j + 1] + a0 * sW[j + 1] + a1 * sW[HID + j + 1] + a2 * sW[2*HID + j + 1]
                             + a3 * sW[3*HID + j + 1] + a4 * sW[4*HID + j + 1];
        op[p] = pack_bf2(fmaxf(t0, 0.f) * dn, fmaxf(t1, 0.f) * dn);
    }
}

// ---------------- fused aggregate + GEMM ----------------
// block = 4 waves = 16 nodes.  Phase 1: wave aggregates 4 nodes (16-lane group per
// edge, 4-deep) into LDS tile g[16][128] bf16.  Phase 2: wave MFMAs the tile against
// 4 of 16 column-tiles of Wc, writes HsHd rows (+brow bias).
__launch_bounds__(256)
__global__ void agg_gemm(const uint4* __restrict__ hs1, const uint2* __restrict__ csr2,
                         const int* __restrict__ rowptr, const float* __restrict__ dis,
                         const uint4* __restrict__ Bf, const float* __restrict__ brow,
                         unsigned short* __restrict__ out, int N) {
    __shared__ uint gt[16][64];
    int wave = threadIdx.x >> 6, lane = threadIdx.x & 63;
    int gl = lane & 15, grp = lane >> 4;
    int nb = blockIdx.x * 16;

    for (int q = 0; q < 4; ++q) {
        int r = wave * 4 + q;
        int n = nb + r;
        if (n < N) {
            int beg = rowptr[n], end = rowptr[n + 1];
            f32x2 acc[4];
            #pragma unroll
            for (int p = 0; p < 4; ++p) acc[p] = mk2(0.f);
            for (int base = beg + grp; base < end; base += 16) {
                int i1 = base + 4, i2 = base + 8, i3 = base + 12;
                int s0 = (int)(csr2[base].x & 0xffffu);
                int s1 = (int)(csr2[(i1 < end) ? i1 : beg].x & 0xffffu);
                int s2 = (int)(csr2[(i2 < end) ? i2 : beg].x & 0xffffu);
                int s3 = (int)(csr2[(i3 < end) ? i3 : beg].x & 0xffffu);
                uint4 v0 = hs1[(size_t)s0 * 16 + gl];
                uint4 v1 = hs1[(size_t)s1 * 16 + gl];
                uint4 v2 = hs1[(size_t)s2 * 16 + gl];
                uint4 v3 = hs1[(size_t)s3 * 16 + gl];
                f32x2 w1 = mk2((i1 < end) ? 1.f : 0.f);
                f32x2 w2 = mk2((i2 < end) ? 1.f : 0.f);
                f32x2 w3 = mk2((i3 < end) ? 1.f : 0.f);
                acc[0] += bf2f(v0.x);  acc[1] += bf2f(v0.y);
                acc[2] += bf2f(v0.z);  acc[3] += bf2f(v0.w);
                acc[0] += bf2f(v1.x) * w1;  acc[1] += bf2f(v1.y) * w1;
                acc[2] += bf2f(v1.z) * w1;  acc[3] += bf2f(v1.w) * w1;
                acc[0] += bf2f(v2.x) * w2;  acc[1] += bf2f(v2.y) * w2;
                acc[2] += bf2f(v2.z) * w2;  acc[3] += bf2f(v2.w) * w2;
                acc[0] += bf2f(v3.x) * w3;  acc[1] += bf2f(v3.y) * w3;
                acc[2] += bf2f(v3.z) * w3;  acc[3] += bf2f(v3.w) * w3;
            }
            #pragma unroll
            for (int p = 0; p < 4; ++p) {
                acc[p] += shfl_xor2(acc[p], 16);
                acc[p] += shfl_xor2(acc[p], 32);
            }
            if (grp == 0) {
                uint4 sv = hs1[(size_t)n * 16 + gl];
                f32x2 dn = mk2(dis[n]);
                f32x2 o0 = (acc[0] + bf2f(sv.x)) * dn;
                f32x2 o1 = (acc[1] + bf2f(sv.y)) * dn;
                f32x2 o2 = (acc[2] + bf2f(sv.z)) * dn;
                f32x2 o3 = (acc[3] + bf2f(sv.w)) * dn;
                gt[r][gl * 4]     = pack_bf2(o0.x, o0.y);
                gt[r][gl * 4 + 1] = pack_bf2(o1.x, o1.y);
                gt[r][gl * 4 + 2] = pack_bf2(o2.x, o2.y);
                gt[r][gl * 4 + 3] = pack_bf2(o3.x, o3.y);
            }
        } else if (grp == 0) {
            gt[r][gl * 4] = 0; gt[r][gl * 4 + 1] = 0;
            gt[r][gl * 4 + 2] = 0; gt[r][gl * 4 + 3] = 0;
        }
    }
    __syncthreads();

    int quad = lane >> 4;
    bf16x8 afr[4];
    #pragma unroll
    for (int kk = 0; kk < 4; ++kk)
        afr[kk] = *(const bf16x8*)&gt[gl][kk * 16 + quad * 4];

    for (int cc = 0; cc < 4; ++cc) {
        int c = wave * 4 + cc;
        f32x4 acc = {0.f, 0.f, 0.f, 0.f};
        #pragma unroll
        for (int kk = 0; kk < 4; ++kk) {
            bf16x8 bfr = *(const bf16x8*)&Bf[(size_t)(c * 4 + kk) * 64 + lane];
            acc = __builtin_amdgcn_mfma_f32_16x16x32_bf16(afr[kk], bfr, acc, 0, 0, 0);
        }
        float bv = brow[c * 16 + gl];
        #pragma unroll
        for (int reg = 0; reg < 4; ++reg) {
            int row = nb + quad * 4 + reg;
            if (row < N)
                out[(size_t)row * 256 + c * 16 + gl] = bf16r(acc[reg] + bv);
        }
    }
}

// edge-parallel edge MLP over dst-sorted csr2 (R10 grid-stride form);
// 16-lane group takes 4 consecutive edges, 16 edges per wave per iteration.
__launch_bounds__(256)
__global__ void edge_mlp_kernel(const uint4* __restrict__ HsHd, const float4* __restrict__ ea,
                                const uint2* __restrict__ csr2,
                                const float* __restrict__ Wb, const float* __restrict__ Wm2,
                                const float* __restrict__ bm2,
                                float* __restrict__ out, int E) {
    int lane = threadIdx.x & 63;
    int gl = lane & 15, grp = lane >> 4;

    f32x2 wb[4][4], w2[4];
    #pragma unroll
    for (int k = 0; k < 4; ++k) {
        const f32x2* wp = (const f32x2*)(Wb + k * HID + gl * 8);
        #pragma unroll
        for (int p = 0; p < 4; ++p) wb[k][p] = wp[p];
    }
    {
        const f32x2* wp = (const f32x2*)(Wm2 + gl * 8);
        #pragma unroll
        for (int p = 0; p < 4; ++p) w2[p] = wp[p];
    }
    float b2v = bm2[0];

    int gwave = (blockIdx.x * blockDim.x + threadIdx.x) >> 6;
    int nw = (gridDim.x * blockDim.x) >> 6;
    for (int base = gwave * 16; base < E; base += nw * 16) {
        int i0 = base + grp * 4;
        uint2 ce[4];
        uint4 hv[4], dv[4];
        float4 eav[4];
        #pragma unroll
        for (int t = 0; t < 4; ++t) {
            int i = i0 + t;
            int j = (i < E) ? i : (E - 1);
            ce[t] = csr2[j];
            hv[t] = HsHd[(size_t)(ce[t].x & 0xffffu) * 32 + gl];
            dv[t] = HsHd[(size_t)(ce[t].x >> 16) * 32 + 16 + gl];
            eav[t] = ea[ce[t].y];
        }
        float pr[4];
        #pragma unroll
        for (int t = 0; t < 4; ++t) {
            uint hu[4] = {hv[t].x, hv[t].y, hv[t].z, hv[t].w};
            uint du[4] = {dv[t].x, dv[t].y, dv[t].z, dv[t].w};
            f32x2 e0 = mk2(eav[t].x), e1 = mk2(eav[t].y);
            f32x2 e2 = mk2(eav[t].z), e3 = mk2(eav[t].w);
            f32x2 p2 = mk2(0.f);
            #pragma unroll
            for (int p = 0; p < 4; ++p) {
                f32x2 tt = bf2f(hu[p]) + bf2f(du[p]);
                tt += e0 * wb[0][p];
                tt += e1 * wb[1][p];
                tt += e2 * wb[2][p];
                tt += e3 * wb[3][p];
                tt = max2z(tt);
                p2 += tt * w2[p];
            }
            pr[t] = p2.x + p2.y;
        }
        #pragma unroll
        for (int o = 1; o <= 8; o <<= 1) {
            #pragma unroll
            for (int t = 0; t < 4; ++t) pr[t] += __shfl_xor(pr[t], o, 64);
        }
        if (gl == 0) {
            #pragma unroll
            for (int t = 0; t < 4; ++t) {
                int i = i0 + t;
                if (i < E)
                    out[ce[t].y] = 1.f / (1.f + exp2f(-1.44269504f * (pr[t] + b2v)));
            }
        }
    }
}

// ---------------- launch ----------------

extern "C" void kernel_launch(void* const* d_in, const int* in_sizes, int n_in,
                              void* d_out, int out_size, void* d_ws, size_t ws_size,
                              hipStream_t stream) {
    const float* x    = (const float*)d_in[0];
    const float* ea   = (const float*)d_in[1];
    const float* W1   = (const float*)d_in[2];
    const float* b1   = (const float*)d_in[3];
    const float* W2   = (const float*)d_in[4];
    const float* b2   = (const float*)d_in[5];
    const float* Wm1  = (const float*)d_in[6];
    const float* bm1  = (const float*)d_in[7];
    const float* Wm2  = (const float*)d_in[8];
    const float* bm2  = (const float*)d_in[9];
    const int*   ei   = (const int*)d_in[10];

    const int N = in_sizes[0] / 5;
    const int E = in_sizes[1] / 4;
    const int* src = ei;
    const int* dst = ei + E;
    float* out = (float*)d_out;

    char* ws = (char*)d_ws;
    size_t off = 0;
    auto alloc = [&](size_t bytes) -> void* {
        void* p = ws + off;
        off = (off + bytes + 255) & ~(size_t)255;
        return p;
    };
    int*    cnt    = (int*)alloc((size_t)N * 4);
    int*    rowptr = (int*)alloc((size_t)(N + 1) * 4);
    int*    bsum   = (int*)alloc(256 * 4);
    float*  dis    = (float*)alloc((size_t)N * 4);
    int*    rank   = (int*)alloc((size_t)(E + 8) * 4);
    uint2*  csr2   = (uint2*)alloc((size_t)(E + 8) * 8);
    uint4*  xps    = (uint4*)alloc((size_t)N * 16);      // bf16 dis*x, 16 B rows
    uint*   hs1    = (uint*)alloc((size_t)N * 64 * 4);   // bf16 layer-1 features
    uint*   HsHd   = (uint*)alloc((size_t)N * 128 * 4);  // bf16 [N][256]
    uint*   fWc    = (uint*)alloc(16384 * 4);
    float*  brow   = (float*)alloc(256 * 4);
    (void)ws_size; (void)n_in; (void)out_size;

    const int NB = (N + 255) / 256;
    const int EB = (E + 255) / 256;

    // setup
    hipMemsetAsync(cnt, 0, (size_t)N * 4, stream);
    prep_kernel<<<65, 256, 0, stream>>>(W2, Wm1, b2, bm1, fWc, brow);
    hist_rank<<<EB, 256, 0, stream>>>(dst, cnt, rank, E);
    scan1<<<NB, 256, 0, stream>>>(cnt, rowptr, bsum, N);
    scan3x<<<NB, 256, 0, stream>>>(cnt, rowptr, bsum, dis, x, xps, N, E, NB);
    scatter2<<<EB, 256, 0, stream>>>(src, dst, rowptr, rank, csr2, E);

    // layer 1 fused: hs1 = dis * relu((S·x)@W1 + b1)
    layer1_kernel<<<NB, 256, 0, stream>>>(xps, csr2, rowptr, dis, W1, b1, hs1, N);

    // fused: g = S·h1 (LDS tile) ; HsHd = g @ Wc + brow
    agg_gemm<<<(N + 15) / 16, 256, 0, stream>>>((const uint4*)hs1, csr2, rowptr, dis,
                                                (const uint4*)fWc, brow,
                                                (unsigned short*)HsHd, N);

    // per-edge MLP + sigmoid, dst-sorted order, grid-stride
    edge_mlp_kernel<<<2048, 256, 0, stream>>>((const uint4*)HsHd, (const float4*)ea, csr2,
                                              Wm1 + 256 * HID, Wm2, bm2, out, E);
}

// Round 14
// 265.296 us; speedup vs baseline: 1.0184x; 1.0003x over previous
//
#include <hip/hip_runtime.h>
#include <math.h>

#define HID 128
typedef unsigned int uint;
typedef __attribute__((ext_vector_type(8))) __bf16 bf16x8;
typedef __attribute__((ext_vector_type(4))) float f32x4;
typedef __attribute__((ext_vector_type(2))) float f32x2;

// ---------------- bf16 helpers (RNE) ----------------

__device__ __forceinline__ uint pack_bf2(float x, float y) {
    union { float f; uint u; } a, b;
    a.f = x; b.f = y;
    uint lo = (a.u + 0x7fffu + ((a.u >> 16) & 1u)) >> 16;
    uint hi = (b.u + 0x7fffu + ((b.u >> 16) & 1u)) & 0xffff0000u;
    return lo | hi;
}

__device__ __forceinline__ unsigned short bf16r(float x) {
    union { float f; uint u; } a; a.f = x;
    return (unsigned short)((a.u + 0x7fffu + ((a.u >> 16) & 1u)) >> 16);
}

__device__ __forceinline__ f32x2 bf2f(uint v) {
    union { uint u[2]; f32x2 f; } r;
    r.u[0] = v << 16;
    r.u[1] = v & 0xffff0000u;
    return r.f;
}

__device__ __forceinline__ f32x2 mk2(float s) { f32x2 r; r.x = s; r.y = s; return r; }
__device__ __forceinline__ f32x2 max2z(f32x2 a) {
    f32x2 r; r.x = fmaxf(a.x, 0.f); r.y = fmaxf(a.y, 0.f); return r;
}
__device__ __forceinline__ f32x2 shfl_xor2(f32x2 v, int m) {
    f32x2 r; r.x = __shfl_xor(v.x, m, 64); r.y = __shfl_xor(v.y, m, 64); return r;
}

// ---------------- setup kernels ----------------

// composite weights (cnt zeroed via hipMemsetAsync):
//   Wc = W2 @ [Wm1_top | Wm1_mid]  (128 x 256), bf16 MFMA frag order
//   brow = b2 @ [Wm1_top | Wm1_mid] + [bm1 | 0]  (256)
__global__ void prep_kernel(const float* __restrict__ W2, const float* __restrict__ Wm1,
                            const float* __restrict__ b2, const float* __restrict__ bm1,
                            uint* __restrict__ fWc, float* __restrict__ brow) {
    int t0 = blockIdx.x * blockDim.x + threadIdx.x;
    if (t0 < 16384) {       // 16 ct * 4 kk * 64 lanes * 4 pairs
        int i = t0;
        int p = i & 3, lane = (i >> 2) & 63, kk = (i >> 8) & 3, ct = i >> 10;
        int k = kk * 32 + (lane >> 4) * 8 + p * 2;
        int n2 = ct * 16 + (lane & 15);
        const float* wmc = (n2 < 128) ? (Wm1 + n2) : (Wm1 + 128 * HID + (n2 - 128));
        const float* w2r0 = W2 + (size_t)k * HID;
        const float* w2r1 = w2r0 + HID;
        float d0 = 0.f, d1 = 0.f;
        for (int j = 0; j < HID; ++j) {
            float wm = wmc[(size_t)j * HID];
            d0 += w2r0[j] * wm;
            d1 += w2r1[j] * wm;
        }
        fWc[i] = pack_bf2(d0, d1);
    } else if (t0 < 16384 + 256) {
        int i = t0 - 16384;
        const float* wmc = (i < 128) ? (Wm1 + i) : (Wm1 + 128 * HID + (i - 128));
        float d = 0.f;
        for (int j = 0; j < HID; ++j) d += b2[j] * wmc[(size_t)j * HID];
        brow[i] = d + ((i < 128) ? bm1[i] : 0.f);
    }
}

// histogram + within-bucket rank (atomic return value)
__global__ void hist_rank(const int* __restrict__ dst, int* __restrict__ cnt,
                          int* __restrict__ rank, int E) {
    int e = blockIdx.x * blockDim.x + threadIdx.x;
    if (e < E) rank[e] = atomicAdd(&cnt[dst[e]], 1);
}

__global__ void scan1(const int* __restrict__ cnt, int* __restrict__ excl,
                      int* __restrict__ bsum, int N) {
    __shared__ int sh[256];
    int tid = threadIdx.x;
    int gid = blockIdx.x * 256 + tid;
    int v = (gid < N) ? cnt[gid] : 0;
    sh[tid] = v;
    __syncthreads();
    for (int o = 1; o < 256; o <<= 1) {
        int t = (tid >= o) ? sh[tid - o] : 0;
        __syncthreads();
        sh[tid] += t;
        __syncthreads();
    }
    if (gid < N) excl[gid] = sh[tid] - v;
    if (tid == 255) bsum[blockIdx.x] = sh[255];
}

// every block redundantly scans bsum in LDS, finalizes rowptr/dis,
// and writes xps[n] = bf16( dis[n] * x[n] ) packed into uint4 (5 dims + pad)
__global__ void scan3x(const int* __restrict__ cnt, int* __restrict__ rowptr,
                       const int* __restrict__ bsum,
                       float* __restrict__ dis, const float* __restrict__ x,
                       uint4* __restrict__ xps, int N, int E, int NB) {
    __shared__ int sh[256];
    __shared__ int ex[256];
    int tid = threadIdx.x;
    int v = (tid < NB) ? bsum[tid] : 0;
    sh[tid] = v;
    __syncthreads();
    for (int o = 1; o < 256; o <<= 1) {
        int t = (tid >= o) ? sh[tid - o] : 0;
        __syncthreads();
        sh[tid] += t;
        __syncthreads();
    }
    ex[tid] = sh[tid] - v;
    __syncthreads();
    int gid = blockIdx.x * 256 + tid;
    if (gid < N) {
        rowptr[gid] = rowptr[gid] + ex[blockIdx.x];
        float dn = rsqrtf((float)cnt[gid] + 1.0f);   // deg incl. self-loop
        dis[gid] = dn;
        const float* xr = x + (size_t)gid * 5;
        uint4 pk;
        pk.x = pack_bf2(dn * xr[0], dn * xr[1]);
        pk.y = pack_bf2(dn * xr[2], dn * xr[3]);
        pk.z = pack_bf2(dn * xr[4], 0.f);
        pk.w = 0u;
        xps[gid] = pk;
    }
    if (gid == N) rowptr[N] = E;
}

// atomic-free scatter: pos = rowptr[dst] + rank; csr2[pos] = (src|dst<<16, eid)
__global__ void scatter2(const int* __restrict__ src, const int* __restrict__ dst,
                         const int* __restrict__ rowptr, const int* __restrict__ rank,
                         uint2* __restrict__ csr2, int E) {
    int e = blockIdx.x * blockDim.x + threadIdx.x;
    if (e < E) {
        int d = dst[e];
        int pos = rowptr[d] + rank[e];
        csr2[pos] = make_uint2((uint)src[e] | ((uint)d << 16), (uint)e);
    }
}

// ---------------- fused layer-1: hs1 = dis * relu( (S·x) @ W1 + b1 ) ----------------
// one thread per node: 5-dim aggregate (bf16 xps, 16 B rows), 128-col LDS-W1 expansion.
__launch_bounds__(256)
__global__ void layer1_kernel(const uint4* __restrict__ xps, const uint2* __restrict__ csr2,
                              const int* __restrict__ rowptr, const float* __restrict__ dis,
                              const float* __restrict__ W1, const float* __restrict__ b1,
                              uint* __restrict__ hs1, int N) {
    __shared__ float sW[5 * HID];
    __shared__ float sb[HID];
    int tid = threadIdx.x;
    for (int i = tid; i < 5 * HID; i += 256) sW[i] = W1[i];
    for (int i = tid; i < HID; i += 256) sb[i] = b1[i];
    __syncthreads();

    int n = blockIdx.x * 256 + tid;
    if (n >= N) return;
    int beg = rowptr[n], end = rowptr[n + 1];
    float a0 = 0.f, a1 = 0.f, a2 = 0.f, a3 = 0.f, a4 = 0.f;
    for (int i = beg; i < end; ++i) {
        int s = (int)(csr2[i].x & 0xffffu);
        uint4 v = xps[s];
        f32x2 v01 = bf2f(v.x), v23 = bf2f(v.y), v4 = bf2f(v.z);
        a0 += v01.x; a1 += v01.y; a2 += v23.x; a3 += v23.y; a4 += v4.x;
    }
    {
        uint4 v = xps[n];
        f32x2 v01 = bf2f(v.x), v23 = bf2f(v.y), v4 = bf2f(v.z);
        a0 += v01.x; a1 += v01.y; a2 += v23.x; a3 += v23.y; a4 += v4.x;
    }
    float dn = dis[n];
    a0 *= dn; a1 *= dn; a2 *= dn; a3 *= dn; a4 *= dn;   // sx row

    uint* op = hs1 + (size_t)n * 64;
    #pragma unroll 4
    for (int p = 0; p < 64; ++p) {
        int j = p * 2;
        float t0 = sb[j]     + a0 * sW[j]     + a1 * sW[HID + j]     + a2 * sW[2*HID + j]
                             + a3 * sW[3*HID + j] + a4 * sW[4*HID + j];
        float t1 = sb[j + 1] + a0 * sW[j + 1] + a1 * sW[HID + j + 1] + a2 * sW[2*HID + j + 1]
                             + a3 * sW[3*HID + j + 1] + a4 * sW[4*HID + j + 1];
        op[p] = pack_bf2(fmaxf(t0, 0.f) * dn, fmaxf(t1, 0.f) * dn);
    }
}

// ---------------- fused aggregate + GEMM ----------------
// block = 4 waves = 16 nodes.  Phase 1: wave aggregates 4 nodes (16-lane group per
// edge, 4-deep) into LDS tile g[16][128] bf16.  Phase 2: wave MFMAs the tile against
// 4 of 16 column-tiles of Wc, writes HsHd rows (+brow bias).
__launch_bounds__(256)
__global__ void agg_gemm(const uint4* __restrict__ hs1, const uint2* __restrict__ csr2,
                         const int* __restrict__ rowptr, const float* __restrict__ dis,
                         const uint4* __restrict__ Bf, const float* __restrict__ brow,
                         unsigned short* __restrict__ out, int N) {
    __shared__ uint gt[16][64];
    int wave = threadIdx.x >> 6, lane = threadIdx.x & 63;
    int gl = lane & 15, grp = lane >> 4;
    int nb = blockIdx.x * 16;

    for (int q = 0; q < 4; ++q) {
        int r = wave * 4 + q;
        int n = nb + r;
        if (n < N) {
            int beg = rowptr[n], end = rowptr[n + 1];
            f32x2 acc[4];
            #pragma unroll
            for (int p = 0; p < 4; ++p) acc[p] = mk2(0.f);
            for (int base = beg + grp; base < end; base += 16) {
                int i1 = base + 4, i2 = base + 8, i3 = base + 12;
                int s0 = (int)(csr2[base].x & 0xffffu);
                int s1 = (int)(csr2[(i1 < end) ? i1 : beg].x & 0xffffu);
                int s2 = (int)(csr2[(i2 < end) ? i2 : beg].x & 0xffffu);
                int s3 = (int)(csr2[(i3 < end) ? i3 : beg].x & 0xffffu);
                uint4 v0 = hs1[(size_t)s0 * 16 + gl];
                uint4 v1 = hs1[(size_t)s1 * 16 + gl];
                uint4 v2 = hs1[(size_t)s2 * 16 + gl];
                uint4 v3 = hs1[(size_t)s3 * 16 + gl];
                f32x2 w1 = mk2((i1 < end) ? 1.f : 0.f);
                f32x2 w2 = mk2((i2 < end) ? 1.f : 0.f);
                f32x2 w3 = mk2((i3 < end) ? 1.f : 0.f);
                acc[0] += bf2f(v0.x);  acc[1] += bf2f(v0.y);
                acc[2] += bf2f(v0.z);  acc[3] += bf2f(v0.w);
                acc[0] += bf2f(v1.x) * w1;  acc[1] += bf2f(v1.y) * w1;
                acc[2] += bf2f(v1.z) * w1;  acc[3] += bf2f(v1.w) * w1;
                acc[0] += bf2f(v2.x) * w2;  acc[1] += bf2f(v2.y) * w2;
                acc[2] += bf2f(v2.z) * w2;  acc[3] += bf2f(v2.w) * w2;
                acc[0] += bf2f(v3.x) * w3;  acc[1] += bf2f(v3.y) * w3;
                acc[2] += bf2f(v3.z) * w3;  acc[3] += bf2f(v3.w) * w3;
            }
            #pragma unroll
            for (int p = 0; p < 4; ++p) {
                acc[p] += shfl_xor2(acc[p], 16);
                acc[p] += shfl_xor2(acc[p], 32);
            }
            if (grp == 0) {
                uint4 sv = hs1[(size_t)n * 16 + gl];
                f32x2 dn = mk2(dis[n]);
                f32x2 o0 = (acc[0] + bf2f(sv.x)) * dn;
                f32x2 o1 = (acc[1] + bf2f(sv.y)) * dn;
                f32x2 o2 = (acc[2] + bf2f(sv.z)) * dn;
                f32x2 o3 = (acc[3] + bf2f(sv.w)) * dn;
                gt[r][gl * 4]     = pack_bf2(o0.x, o0.y);
                gt[r][gl * 4 + 1] = pack_bf2(o1.x, o1.y);
                gt[r][gl * 4 + 2] = pack_bf2(o2.x, o2.y);
                gt[r][gl * 4 + 3] = pack_bf2(o3.x, o3.y);
            }
        } else if (grp == 0) {
            gt[r][gl * 4] = 0; gt[r][gl * 4 + 1] = 0;
            gt[r][gl * 4 + 2] = 0; gt[r][gl * 4 + 3] = 0;
        }
    }
    __syncthreads();

    int quad = lane >> 4;
    bf16x8 afr[4];
    #pragma unroll
    for (int kk = 0; kk < 4; ++kk)
        afr[kk] = *(const bf16x8*)&gt[gl][kk * 16 + quad * 4];

    for (int cc = 0; cc < 4; ++cc) {
        int c = wave * 4 + cc;
        f32x4 acc = {0.f, 0.f, 0.f, 0.f};
        #pragma unroll
        for (int kk = 0; kk < 4; ++kk) {
            bf16x8 bfr = *(const bf16x8*)&Bf[(size_t)(c * 4 + kk) * 64 + lane];
            acc = __builtin_amdgcn_mfma_f32_16x16x32_bf16(afr[kk], bfr, acc, 0, 0, 0);
        }
        float bv = brow[c * 16 + gl];
        #pragma unroll
        for (int reg = 0; reg < 4; ++reg) {
            int row = nb + quad * 4 + reg;
            if (row < N)
                out[(size_t)row * 256 + c * 16 + gl] = bf16r(acc[reg] + bv);
        }
    }
}

// edge-parallel edge MLP over dst-sorted csr2 (grid-stride form);
// 16-lane group takes 4 consecutive edges, 16 edges per wave per iteration.
__launch_bounds__(256)
__global__ void edge_mlp_kernel(const uint4* __restrict__ HsHd, const float4* __restrict__ ea,
                                const uint2* __restrict__ csr2,
                                const float* __restrict__ Wb, const float* __restrict__ Wm2,
                                const float* __restrict__ bm2,
                                float* __restrict__ out, int E) {
    int lane = threadIdx.x & 63;
    int gl = lane & 15, grp = lane >> 4;

    f32x2 wb[4][4], w2[4];
    #pragma unroll
    for (int k = 0; k < 4; ++k) {
        const f32x2* wp = (const f32x2*)(Wb + k * HID + gl * 8);
        #pragma unroll
        for (int p = 0; p < 4; ++p) wb[k][p] = wp[p];
    }
    {
        const f32x2* wp = (const f32x2*)(Wm2 + gl * 8);
        #pragma unroll
        for (int p = 0; p < 4; ++p) w2[p] = wp[p];
    }
    float b2v = bm2[0];

    int gwave = (blockIdx.x * blockDim.x + threadIdx.x) >> 6;
    int nw = (gridDim.x * blockDim.x) >> 6;
    for (int base = gwave * 16; base < E; base += nw * 16) {
        int i0 = base + grp * 4;
        uint2 ce[4];
        uint4 hv[4], dv[4];
        float4 eav[4];
        #pragma unroll
        for (int t = 0; t < 4; ++t) {
            int i = i0 + t;
            int j = (i < E) ? i : (E - 1);
            ce[t] = csr2[j];
            hv[t] = HsHd[(size_t)(ce[t].x & 0xffffu) * 32 + gl];
            dv[t] = HsHd[(size_t)(ce[t].x >> 16) * 32 + 16 + gl];
            eav[t] = ea[ce[t].y];
        }
        float pr[4];
        #pragma unroll
        for (int t = 0; t < 4; ++t) {
            uint hu[4] = {hv[t].x, hv[t].y, hv[t].z, hv[t].w};
            uint du[4] = {dv[t].x, dv[t].y, dv[t].z, dv[t].w};
            f32x2 e0 = mk2(eav[t].x), e1 = mk2(eav[t].y);
            f32x2 e2 = mk2(eav[t].z), e3 = mk2(eav[t].w);
            f32x2 p2 = mk2(0.f);
            #pragma unroll
            for (int p = 0; p < 4; ++p) {
                f32x2 tt = bf2f(hu[p]) + bf2f(du[p]);
                tt += e0 * wb[0][p];
                tt += e1 * wb[1][p];
                tt += e2 * wb[2][p];
                tt += e3 * wb[3][p];
                tt = max2z(tt);
                p2 += tt * w2[p];
            }
            pr[t] = p2.x + p2.y;
        }
        #pragma unroll
        for (int o = 1; o <= 8; o <<= 1) {
            #pragma unroll
            for (int t = 0; t < 4; ++t) pr[t] += __shfl_xor(pr[t], o, 64);
        }
        if (gl == 0) {
            #pragma unroll
            for (int t = 0; t < 4; ++t) {
                int i = i0 + t;
                if (i < E)
                    out[ce[t].y] = 1.f / (1.f + exp2f(-1.44269504f * (pr[t] + b2v)));
            }
        }
    }
}

// ---------------- launch ----------------

extern "C" void kernel_launch(void* const* d_in, const int* in_sizes, int n_in,
                              void* d_out, int out_size, void* d_ws, size_t ws_size,
                              hipStream_t stream) {
    const float* x    = (const float*)d_in[0];
    const float* ea   = (const float*)d_in[1];
    const float* W1   = (const float*)d_in[2];
    const float* b1   = (const float*)d_in[3];
    const float* W2   = (const float*)d_in[4];
    const float* b2   = (const float*)d_in[5];
    const float* Wm1  = (const float*)d_in[6];
    const float* bm1  = (const float*)d_in[7];
    const float* Wm2  = (const float*)d_in[8];
    const float* bm2  = (const float*)d_in[9];
    const int*   ei   = (const int*)d_in[10];

    const int N = in_sizes[0] / 5;
    const int E = in_sizes[1] / 4;
    const int* src = ei;
    const int* dst = ei + E;
    float* out = (float*)d_out;

    char* ws = (char*)d_ws;
    size_t off = 0;
    auto alloc = [&](size_t bytes) -> void* {
        void* p = ws + off;
        off = (off + bytes + 255) & ~(size_t)255;
        return p;
    };
    int*    cnt    = (int*)alloc((size_t)N * 4);
    int*    rowptr = (int*)alloc((size_t)(N + 1) * 4);
    int*    bsum   = (int*)alloc(256 * 4);
    float*  dis    = (float*)alloc((size_t)N * 4);
    int*    rank   = (int*)alloc((size_t)(E + 8) * 4);
    uint2*  csr2   = (uint2*)alloc((size_t)(E + 8) * 8);
    uint4*  xps    = (uint4*)alloc((size_t)N * 16);      // bf16 dis*x, 16 B rows
    uint*   hs1    = (uint*)alloc((size_t)N * 64 * 4);   // bf16 layer-1 features
    uint*   HsHd   = (uint*)alloc((size_t)N * 128 * 4);  // bf16 [N][256]
    uint*   fWc    = (uint*)alloc(16384 * 4);
    float*  brow   = (float*)alloc(256 * 4);
    (void)ws_size; (void)n_in; (void)out_size;

    const int NB = (N + 255) / 256;
    const int EB = (E + 255) / 256;

    // setup
    hipMemsetAsync(cnt, 0, (size_t)N * 4, stream);
    prep_kernel<<<65, 256, 0, stream>>>(W2, Wm1, b2, bm1, fWc, brow);
    hist_rank<<<EB, 256, 0, stream>>>(dst, cnt, rank, E);
    scan1<<<NB, 256, 0, stream>>>(cnt, rowptr, bsum, N);
    scan3x<<<NB, 256, 0, stream>>>(cnt, rowptr, bsum, dis, x, xps, N, E, NB);
    scatter2<<<EB, 256, 0, stream>>>(src, dst, rowptr, rank, csr2, E);

    // layer 1 fused: hs1 = dis * relu((S·x)@W1 + b1)
    layer1_kernel<<<NB, 256, 0, stream>>>(xps, csr2, rowptr, dis, W1, b1, hs1, N);

    // fused: g = S·h1 (LDS tile) ; HsHd = g @ Wc + brow
    agg_gemm<<<(N + 15) / 16, 256, 0, stream>>>((const uint4*)hs1, csr2, rowptr, dis,
                                                (const uint4*)fWc, brow,
                                                (unsigned short*)HsHd, N);

    // per-edge MLP + sigmoid, dst-sorted order, grid-stride
    edge_mlp_kernel<<<2048, 256, 0, stream>>>((const uint4*)HsHd, (const float4*)ea, csr2,
                                              Wm1 + 256 * HID, Wm2, bm2, out, E);
}